// Round 8
// baseline (106.614 us; speedup 1.0000x reference)
//
#include <hip/hip_runtime.h>
#include <hip/hip_bf16.h>

// SEQ=512, BATCH=64, DIM=512, MAXLEN=512, E=655360
// out[b][u][s] = edge(b,u,s) ? exp(scale) / (T_e + 1e-10*(T-T_e)) : 0  (max cancels)
// scale[s,b,m] = sum_d M[s,b,d] * W[m,d]
//
// Primary: prep (M,W->bf16 + edge bitmap), then fused_attn_p:
//   block = (b, m-tile 64) x s=512; 1024 threads = 16 waves, wave owns a
//   32-row s-band. A (W tile) resident in LDS 64 KB (XOR-swizzled, conflict-
//   free staged); B bands DMA'd 3-deep via global_load_lds, per-wave counted
//   vmcnt, ZERO barriers in K-loop. LDS = 160 KiB exactly -> 4 waves/SIMD.
// Fallback (round-6 path) if ws too small.

#define SEQ 512
#define BATCH 64
#define DIM 512
#define MAXLEN 512

typedef __attribute__((ext_vector_type(8))) __bf16 bf16x8;
typedef __attribute__((ext_vector_type(4))) float f32x4;

__device__ __forceinline__ unsigned cvt_pk(float lo, float hi) {
    unsigned r;
    asm("v_cvt_pk_bf16_f32 %0, %1, %2" : "=v"(r) : "v"(lo), "v"(hi));
    return r;
}

__device__ __forceinline__ void gload16(const void* g, void* l) {
    __builtin_amdgcn_global_load_lds(
        (const __attribute__((address_space(1))) void*)g,
        (__attribute__((address_space(3))) void*)l, 16, 0, 0);
}

// ================= primary path =================

// blocks 0..8191: cvt M; 8192..10751: edge scatter; 10752..10879: cvt W
__global__ __launch_bounds__(256) void prep(const float* __restrict__ Mg,
                                            const float* __restrict__ Wg,
                                            const int* __restrict__ eb,
                                            const int* __restrict__ eu,
                                            const int* __restrict__ ev,
                                            unsigned short* __restrict__ Mbf,
                                            unsigned short* __restrict__ Wbf,
                                            unsigned* __restrict__ bits, int E) {
    int blk = blockIdx.x;
    if (blk < 8192) {
        size_t id = (size_t)blk * 256 + threadIdx.x;
        const float4* s = (const float4*)Mg + id * 2;
        float4 a = s[0], c = s[1];
        uint4 o;
        o.x = cvt_pk(a.x, a.y); o.y = cvt_pk(a.z, a.w);
        o.z = cvt_pk(c.x, c.y); o.w = cvt_pk(c.z, c.w);
        ((uint4*)Mbf)[id] = o;
    } else if (blk < 10752) {
        int i = (blk - 8192) * 256 + threadIdx.x;
        if (i < E)
            atomicOr(&bits[(eb[i] * MAXLEN + eu[i]) * 16 + (ev[i] >> 5)],
                     1u << (ev[i] & 31));
    } else {
        size_t id = (size_t)(blk - 10752) * 256 + threadIdx.x;
        const float4* s = (const float4*)Wg + id * 2;
        float4 a = s[0], c = s[1];
        uint4 o;
        o.x = cvt_pk(a.x, a.y); o.y = cvt_pk(a.z, a.w);
        o.z = cvt_pk(c.x, c.y); o.w = cvt_pk(c.z, c.w);
        ((uint4*)Wbf)[id] = o;
    }
}

__global__ __launch_bounds__(1024, 1) void fused_attn_p(
    const unsigned short* __restrict__ Mbf,
    const unsigned short* __restrict__ Wbf,
    const unsigned int* __restrict__ bitsG,
    float* __restrict__ out) {
    // LDS (160 KiB exactly):
    //   [0,65536):       A 64 rows x 1024 B, LDS chunk ch holds src chunk ch^(r&7)
    //   [65536,163840):  B 3 bufs x 16 waves x (32 rows x 64 B); LDS chunk ch of
    //                    row r holds src chunk ch^((r>>1)&3)
    //   epilogue overlays: red float2[64][16] at +65536; stg [16][516] f32 at 0
    __shared__ __align__(16) char lds[163840];

    const int g = blockIdx.x;
    const int work = (g & 7) * 64 + (g >> 3);   // bijective [0,512): same-b -> one XCD
    const int b  = work >> 3;
    const int m0 = (work & 7) * 64;

    const int t = threadIdx.x, lane = t & 63, wv = t >> 6;   // wv 0..15
    const int lg = lane >> 4, lc = lane & 15;

    // ---- B DMA source (swizzle folded into per-lane source chunk) ----
    const int srow0 = wv * 32 + (lane >> 2);           // + q*16
    const int cs    = (lane & 3) ^ ((lane >> 3) & 3);
    const char* bsrc = (const char*)Mbf + ((size_t)srow0 * BATCH + b) * (DIM * 2) + cs * 16;
    char* const bband = lds + 65536 + wv * 2048;       // + p*32768 + q*1024

    // prologue: B(0), B(1), B(2)
#pragma unroll
    for (int p = 0; p < 3; ++p)
#pragma unroll
        for (int q = 0; q < 2; ++q)
            gload16(bsrc + p * 64 + ((size_t)q << 20), bband + p * 32768 + q * 1024);

    // ---- stage A tile 64x512 bf16, conflict-free write pattern ----
    {
        const char* wb = (const char*)Wbf + (size_t)m0 * 1024;
        const int r = t >> 4;            // 0..63
        const int th = t & 15;
#pragma unroll
        for (int i = 0; i < 4; ++i) {
            int chw = i * 16 + th;               // write chunk: lanes 0..7 span 8 slots
            int csA = chw ^ (r & 7);             // source chunk
            uint4 v = *(const uint4*)(wb + (size_t)r * 1024 + csA * 16);
            *(uint4*)(lds + r * 1024 + chw * 16) = v;
        }
    }
    __syncthreads();

    f32x4 acc[4][2] = {};

#pragma unroll
    for (int ks = 0; ks < 16; ++ks) {
        if (ks <= 13)      asm volatile("s_waitcnt vmcnt(4)" ::: "memory");
        else if (ks == 14) asm volatile("s_waitcnt vmcnt(2)" ::: "memory");
        else               asm volatile("s_waitcnt vmcnt(0)" ::: "memory");

        const char* bb = lds + 65536 + (ks % 3) * 32768 + wv * 2048;
        bf16x8 af[4], bfr[2];
#pragma unroll
        for (int i = 0; i < 4; ++i) {
            int ch = (ks * 4 + lg) ^ (lc & 7);
            af[i] = *(const bf16x8*)(lds + (i * 16 + lc) * 1024 + ch * 16);
        }
#pragma unroll
        for (int j = 0; j < 2; ++j) {
            int ch = lg ^ ((lc >> 1) & 3);
            bfr[j] = *(const bf16x8*)(bb + (j * 16 + lc) * 64 + ch * 16);
        }
        __builtin_amdgcn_s_setprio(1);
#pragma unroll
        for (int i = 0; i < 4; ++i)
#pragma unroll
            for (int j = 0; j < 2; ++j)
                acc[i][j] = __builtin_amdgcn_mfma_f32_16x16x32_bf16(af[i], bfr[j], acc[i][j], 0, 0, 0);
        __builtin_amdgcn_s_setprio(0);

        if (ks <= 12) {
            __builtin_amdgcn_sched_barrier(0);   // DMA issues stay after this step's reads
#pragma unroll
            for (int q = 0; q < 2; ++q)
                gload16(bsrc + (ks + 3) * 64 + ((size_t)q << 20),
                        bband + (ks % 3) * 32768 + q * 1024);
        }
    }
    __syncthreads();   // all waves out of B region before red overlay

    float2* const red = (float2*)(lds + 65536);   // [64][16]
    const unsigned int* bitsRow = bitsG + (size_t)(b * MAXLEN + m0) * 16;

    // ---- pass 1: exp + per-wave (T,Te) partials ----
#pragma unroll
    for (int i = 0; i < 4; ++i) {
#pragma unroll
        for (int r = 0; r < 4; ++r) {
            const int m = i * 16 + lg * 4 + r;
            const unsigned word = bitsRow[m * 16 + wv];
            float T = 0.f, Te = 0.f;
#pragma unroll
            for (int j = 0; j < 2; ++j) {
                float e = __expf(acc[i][j][r]);
                acc[i][j][r] = e;
                float bit = (float)((word >> (j * 16 + lc)) & 1u);
                T += e; Te += e * bit;
            }
#pragma unroll
            for (int off = 1; off < 16; off <<= 1) {
                T  += __shfl_xor(T, off);
                Te += __shfl_xor(Te, off);
            }
            if (lc == 0) red[m * 16 + wv] = make_float2(T, Te);
        }
    }
    __syncthreads();

    // ---- pass 2: masked scale -> LDS transpose -> coalesced full-line stores ----
    float* const stg = (float*)lds;               // [16][516]
    for (int i = 0; i < 4; ++i) {
#pragma unroll
        for (int r = 0; r < 4; ++r) {
            const int m = i * 16 + lg * 4 + r;
            float T = 0.f, Te = 0.f;
#pragma unroll
            for (int q = 0; q < 16; ++q) {
                float2 p = red[m * 16 + q];
                T += p.x; Te += p.y;
            }
            const float inv = 1.0f / (Te + 1e-10f * (T - Te));
            const unsigned word = bitsRow[m * 16 + wv];
#pragma unroll
            for (int j = 0; j < 2; ++j) {
                unsigned bit = (word >> (j * 16 + lc)) & 1u;
                stg[(lg * 4 + r) * 516 + wv * 32 + j * 16 + lc] =
                    bit ? acc[i][j][r] * inv : 0.0f;
            }
        }
        __syncthreads();
#pragma unroll
        for (int it = 0; it < 2; ++it) {
            int f = it * 1024 + t;
            int ml = f >> 7;                      // 0..15
            int s4 = (f & 127) * 4;
            float4 v = *(const float4*)(stg + ml * 516 + s4);
            *(float4*)(out + ((size_t)(b * MAXLEN + m0 + i * 16 + ml)) * SEQ + s4) = v;
        }
        __syncthreads();
    }
}

// ================= fallback path (round-6, known-correct) =================

__global__ __launch_bounds__(256) void edge_scatter(const int* __restrict__ eb,
                                                    const int* __restrict__ eu,
                                                    const int* __restrict__ ev,
                                                    unsigned int* __restrict__ bits,
                                                    int E) {
    int i = blockIdx.x * 256 + threadIdx.x;
    if (i < E) {
        int b = eb[i], u = eu[i], v = ev[i];
        atomicOr(&bits[(b * MAXLEN + u) * 16 + (v >> 5)], 1u << (v & 31));
    }
}

__global__ __launch_bounds__(256) void cvt_w(const float* __restrict__ src,
                                             unsigned short* __restrict__ dst) {
    int i = blockIdx.x * 256 + threadIdx.x;
    const float4* s = (const float4*)src + (size_t)i * 2;
    float4 a = s[0], c = s[1];
    uint4 o;
    o.x = cvt_pk(a.x, a.y); o.y = cvt_pk(a.z, a.w);
    o.z = cvt_pk(c.x, c.y); o.w = cvt_pk(c.z, c.w);
    ((uint4*)dst)[i] = o;
}

__global__ __launch_bounds__(512, 4) void fused_attn(
    const float* __restrict__ Mg,
    const unsigned short* __restrict__ Wbf,
    const unsigned int* __restrict__ bitsG,
    float* __restrict__ out) {
    __shared__ __align__(16) char lds[81920];
    char* bufB  = lds;
    char* curA  = lds + 65536;
    char* nxtA  = lds + 69632;
    float2* red = (float2*)(lds + 73728);
    unsigned* bitsL = (unsigned*)(lds + 77824);
    float* stg = (float*)lds;

    const int g = blockIdx.x;
    const int work = (g & 7) * 64 + (g >> 3);
    const int b  = work >> 3;
    const int m0 = (work & 7) * 64;

    const int t = threadIdx.x;
    const int lane = t & 63;
    const int wv = t >> 6;
    const int lg = lane >> 4;
    const int lc = lane & 15;

    if (t < 256)
        ((uint4*)bitsL)[t] = ((const uint4*)(bitsG + (size_t)(b * MAXLEN + m0) * 16))[t];

    const int brs = lane >> 3;
    const int bc  = (lane & 7) ^ brs;
    const int ars = lane >> 2;
    const int ac  = (lane & 3) ^ ((ars >> 2) & 3);

    const char* const MgB = (const char*)Mg + (size_t)b * DIM * 4;
    const char* const WbB = (const char*)Wbf + (size_t)m0 * DIM * 2;

    f32x4 acc[4][4] = {};

    if (wv < 4)
        gload16(WbB + (size_t)(wv * 16 + ars) * (DIM * 2) + ac * 16, curA + wv * 16 * 64);
    __syncthreads();

#pragma unroll 2
    for (int ks = 0; ks < 16; ++ks) {
        const int kb = ks * 128;
#pragma unroll
        for (int q = 0; q < 8; ++q) {
            int r = wv * 64 + q * 8 + brs;
            gload16(MgB + (size_t)r * (BATCH * DIM * 4) + kb + bc * 16,
                    bufB + (wv * 64 + q * 8) * 128);
        }
        const bool pfA = (ks < 15) && (wv < 4);
        if (pfA)
            gload16(WbB + (size_t)(wv * 16 + ars) * (DIM * 2) + (ks + 1) * 64 + ac * 16,
                    nxtA + wv * 16 * 64);
        if (pfA) asm volatile("s_waitcnt vmcnt(1)" ::: "memory");
        else     asm volatile("s_waitcnt vmcnt(0)" ::: "memory");

        const int fxr = (lc >> 2) & 3;
        bf16x8 af[4];
#pragma unroll
        for (int i = 0; i < 4; ++i)
            af[i] = *(const bf16x8*)(curA + (i * 16 + lc) * 64 + ((lg ^ fxr) * 16));
        const int bxr = lc & 7;
        bf16x8 bfr[4];
#pragma unroll
        for (int j = 0; j < 4; ++j) {
            const char* rowp = bufB + (wv * 64 + j * 16 + lc) * 128;
            f32x4 x = *(const f32x4*)(rowp + (((2 * lg) ^ bxr) * 16));
            f32x4 y = *(const f32x4*)(rowp + (((2 * lg + 1) ^ bxr) * 16));
            uint4 pk;
            pk.x = cvt_pk(x[0], x[1]); pk.y = cvt_pk(x[2], x[3]);
            pk.z = cvt_pk(y[0], y[1]); pk.w = cvt_pk(y[2], y[3]);
            bfr[j] = __builtin_bit_cast(bf16x8, pk);
        }
#pragma unroll
        for (int i = 0; i < 4; ++i)
#pragma unroll
            for (int j = 0; j < 4; ++j)
                acc[i][j] = __builtin_amdgcn_mfma_f32_16x16x32_bf16(af[i], bfr[j], acc[i][j], 0, 0, 0);
        __syncthreads();
        { char* tmp = curA; curA = nxtA; nxtA = tmp; }
    }

#pragma unroll
    for (int i = 0; i < 4; ++i) {
#pragma unroll
        for (int r = 0; r < 4; ++r) {
            const int m = i * 16 + lg * 4 + r;
            const uint2 wbt = *(const uint2*)(bitsL + m * 16 + wv * 2);
            float T = 0.f, Te = 0.f;
#pragma unroll
            for (int j = 0; j < 4; ++j) {
                float e = __expf(acc[i][j][r]);
                acc[i][j][r] = e;
                unsigned word = (j & 2) ? wbt.y : wbt.x;
                float bit = (float)((word >> ((j & 1) * 16 + lc)) & 1u);
                T += e; Te += e * bit;
            }
#pragma unroll
            for (int off = 1; off < 16; off <<= 1) {
                T  += __shfl_xor(T, off);
                Te += __shfl_xor(Te, off);
            }
            if (lc == 0) red[m * 8 + wv] = make_float2(T, Te);
        }
    }
    __syncthreads();

    for (int i = 0; i < 4; ++i) {
        float inv[4];
        uint2 wbt2[4];
#pragma unroll
        for (int r = 0; r < 4; ++r) {
            const int m = i * 16 + lg * 4 + r;
            float T = 0.f, Te = 0.f;
#pragma unroll
            for (int q = 0; q < 8; ++q) {
                float2 p = red[m * 8 + q];
                T += p.x; Te += p.y;
            }
            inv[r] = 1.0f / (Te + 1e-10f * (T - Te));
            wbt2[r] = *(const uint2*)(bitsL + m * 16 + wv * 2);
        }
#pragma unroll
        for (int r = 0; r < 4; ++r) {
#pragma unroll
            for (int j = 0; j < 4; ++j) {
                unsigned word = (j & 2) ? wbt2[r].y : wbt2[r].x;
                unsigned bit = (word >> ((j & 1) * 16 + lc)) & 1u;
                stg[(lg * 4 + r) * 516 + wv * 64 + j * 16 + lc] =
                    bit ? acc[i][j][r] * inv[r] : 0.0f;
            }
        }
        __syncthreads();
#pragma unroll
        for (int it = 0; it < 4; ++it) {
            int f = it * 512 + t;
            int ml = f >> 7;
            int s4 = (f & 127) * 4;
            float4 v = *(const float4*)(stg + ml * 516 + s4);
            *(float4*)(out + ((size_t)(b * MAXLEN + m0 + i * 16 + ml)) * SEQ + s4) = v;
        }
        __syncthreads();
    }
}

// ================= launch =================

extern "C" void kernel_launch(void* const* d_in, const int* in_sizes, int n_in,
                              void* d_out, int out_size, void* d_ws, size_t ws_size,
                              hipStream_t stream) {
    const float* Mg = (const float*)d_in[0];
    const float* Wg = (const float*)d_in[1];
    // d_in[2] = lengths (unused by reference)
    const int* eb = (const int*)d_in[3];
    const int* eu = (const int*)d_in[4];
    const int* ev = (const int*)d_in[5];
    const int E = in_sizes[3];

    float* out = (float*)d_out;
    unsigned int* bits = (unsigned int*)d_ws;
    const size_t MBF_OFF = 2097152;                       // 2 MB bitmap
    const size_t WBF_OFF = MBF_OFF + 33554432;            // + 32 MB Mbf
    const size_t NEED    = WBF_OFF + 524288;              // + 0.5 MB Wbf

    hipMemsetAsync(bits, 0, (size_t)BATCH * MAXLEN * 16 * sizeof(unsigned int), stream);

    if (ws_size >= NEED) {
        unsigned short* Mbf = (unsigned short*)((char*)d_ws + MBF_OFF);
        unsigned short* Wbf = (unsigned short*)((char*)d_ws + WBF_OFF);
        prep<<<10880, 256, 0, stream>>>(Mg, Wg, eb, eu, ev, Mbf, Wbf, bits, E);
        fused_attn_p<<<512, 1024, 0, stream>>>(Mbf, Wbf, bits, out);
    } else {
        unsigned short* Wbf = (unsigned short*)((char*)d_ws + MBF_OFF);
        edge_scatter<<<(E + 255) / 256, 256, 0, stream>>>(eb, eu, ev, bits, E);
        cvt_w<<<128, 256, 0, stream>>>(Wg, Wbf);
        fused_attn<<<512, 512, 0, stream>>>(Mg, Wbf, bits, out);
    }
}

// Round 9
// 102.043 us; speedup vs baseline: 1.0448x; 1.0448x over previous
//
#include <hip/hip_runtime.h>
#include <hip/hip_bf16.h>

// SEQ=512, BATCH=64, DIM=512, MAXLEN=512, E=655360
// out[b][u][s] = edge(b,u,s) ? exp(scale) / (T_e + 1e-10*(T-T_e)) : 0  (max cancels)
// scale[s,b,m] = sum_d M[s,b,d] * W[m,d]
//
// Single fused kernel (no pre-convert pass): block = (b, m-tile 128) x s=512,
// 512 threads = 8 waves, wave-tile 64m x 128s (acc[4][8] -> 42.7 flop/LDS-byte).
// K-loop: single-buffer LDS, 2 barriers/step, global f32 prefetched into regs
// one step ahead, f32->bf16 cvt in-reg. LDS chunk swizzle ^((row>>1)&3) -> <=2-way.

#define SEQ 512
#define BATCH 64
#define DIM 512
#define MAXLEN 512

typedef __attribute__((ext_vector_type(8))) __bf16 bf16x8;
typedef __attribute__((ext_vector_type(4))) float f32x4;

__device__ __forceinline__ unsigned cvt_pk(float lo, float hi) {
    unsigned r;
    asm("v_cvt_pk_bf16_f32 %0, %1, %2" : "=v"(r) : "v"(lo), "v"(hi));
    return r;
}

// ---------------- edge bitmap scatter ----------------
__global__ __launch_bounds__(256) void edge_scatter(const int* __restrict__ eb,
                                                    const int* __restrict__ eu,
                                                    const int* __restrict__ ev,
                                                    unsigned int* __restrict__ bits,
                                                    int E) {
    int i = blockIdx.x * 256 + threadIdx.x;
    if (i < E) {
        int b = eb[i], u = eu[i], v = ev[i];
        atomicOr(&bits[(b * MAXLEN + u) * 16 + (v >> 5)], 1u << (v & 31));
    }
}

// ---------------- fused GEMM + softmax + edge renorm ----------------
__global__ __launch_bounds__(512, 2) void fused_attn(
    const float* __restrict__ Mg,
    const float* __restrict__ Wg,
    const unsigned int* __restrict__ bitsG,
    float* __restrict__ out) {
    // LDS map (53248 B):
    //   At    [0,8192):      A bf16 [128 rows][64 B], phys chunk p = c ^ ((row>>1)&3)
    //   Bt    [8192,40960):  B bf16 [512 rows][64 B], same swizzle
    //   red   [40960,45056): float2[128][4]  (T,Te) partials per s-quarter
    //   bitsL [45056,53248): uint[128][16]
    //   stg overlay [0,33024): f32 [16][516] epilogue transpose
    __shared__ __align__(16) char lds[53248];
    char* const At = lds;
    char* const Bt = lds + 8192;
    float2* const red = (float2*)(lds + 40960);
    unsigned* const bitsL = (unsigned*)(lds + 45056);
    float* const stg = (float*)lds;

    // XCD-concentrating remap: 4 m-tiles of each b contiguous -> same XCD L2
    const int g = blockIdx.x;
    const int work = (g & 7) * 32 + (g >> 3);   // bijective over [0,256)
    const int b  = work >> 2;
    const int m0 = (work & 3) * 128;

    const int t = threadIdx.x, lane = t & 63, wv = t >> 6;
    const int h = wv >> 2;      // m half (64 rows)
    const int q = wv & 3;       // s quarter (128 cols)
    const int lg = lane >> 4, lc = lane & 15;

    // stage edge bits: 128 rows x 16 words = 512 uint4, one per thread
    ((uint4*)bitsL)[t] = ((const uint4*)(bitsG + (size_t)(b * MAXLEN + m0) * 16))[t];

    // staging sources: B row t (s-row), A row t>>2 chunk t&3
    const float* const mrow = Mg + ((size_t)t * BATCH + b) * DIM;
    const float* const arow = Wg + (size_t)(m0 + (t >> 2)) * DIM + (t & 3) * 8;
    char* const aw = At + (t >> 2) * 64 + (((t & 3) ^ ((t >> 3) & 3)) * 16);
    char* const bwRow = Bt + t * 64;
    const int bswz = (t >> 1) & 3;

    // prologue: prefetch ks=0 into regs
    float4 aR0 = *(const float4*)(arow);
    float4 aR1 = *(const float4*)(arow + 4);
    float4 bR0 = *(const float4*)(mrow);
    float4 bR1 = *(const float4*)(mrow + 4);
    float4 bR2 = *(const float4*)(mrow + 8);
    float4 bR3 = *(const float4*)(mrow + 12);
    float4 bR4 = *(const float4*)(mrow + 16);
    float4 bR5 = *(const float4*)(mrow + 20);
    float4 bR6 = *(const float4*)(mrow + 24);
    float4 bR7 = *(const float4*)(mrow + 28);

    f32x4 acc[4][8] = {};

    for (int ks = 0; ks < 16; ++ks) {
        if (ks) __syncthreads();   // all waves done reading previous tiles

        // ---- cvt + LDS write current step ----
        uint4 av;
        av.x = cvt_pk(aR0.x, aR0.y); av.y = cvt_pk(aR0.z, aR0.w);
        av.z = cvt_pk(aR1.x, aR1.y); av.w = cvt_pk(aR1.z, aR1.w);
        *(uint4*)aw = av;
        uint4 bv;
        bv.x = cvt_pk(bR0.x, bR0.y); bv.y = cvt_pk(bR0.z, bR0.w);
        bv.z = cvt_pk(bR1.x, bR1.y); bv.w = cvt_pk(bR1.z, bR1.w);
        *(uint4*)(bwRow + ((0 ^ bswz) * 16)) = bv;
        bv.x = cvt_pk(bR2.x, bR2.y); bv.y = cvt_pk(bR2.z, bR2.w);
        bv.z = cvt_pk(bR3.x, bR3.y); bv.w = cvt_pk(bR3.z, bR3.w);
        *(uint4*)(bwRow + ((1 ^ bswz) * 16)) = bv;
        bv.x = cvt_pk(bR4.x, bR4.y); bv.y = cvt_pk(bR4.z, bR4.w);
        bv.z = cvt_pk(bR5.x, bR5.y); bv.w = cvt_pk(bR5.z, bR5.w);
        *(uint4*)(bwRow + ((2 ^ bswz) * 16)) = bv;
        bv.x = cvt_pk(bR6.x, bR6.y); bv.y = cvt_pk(bR6.z, bR6.w);
        bv.z = cvt_pk(bR7.x, bR7.y); bv.w = cvt_pk(bR7.z, bR7.w);
        *(uint4*)(bwRow + ((3 ^ bswz) * 16)) = bv;

        // ---- prefetch next step into regs (in flight across the MFMAs) ----
        if (ks + 1 < 16) {
            const int k1 = (ks + 1) * 32;
            aR0 = *(const float4*)(arow + k1);
            aR1 = *(const float4*)(arow + k1 + 4);
            bR0 = *(const float4*)(mrow + k1);
            bR1 = *(const float4*)(mrow + k1 + 4);
            bR2 = *(const float4*)(mrow + k1 + 8);
            bR3 = *(const float4*)(mrow + k1 + 12);
            bR4 = *(const float4*)(mrow + k1 + 16);
            bR5 = *(const float4*)(mrow + k1 + 20);
            bR6 = *(const float4*)(mrow + k1 + 24);
            bR7 = *(const float4*)(mrow + k1 + 28);
        }
        __syncthreads();           // tiles visible

        // ---- fragments + 32 MFMA ----
        const int psw = (lc >> 1) & 3;
        bf16x8 af[4], bfr[8];
#pragma unroll
        for (int i = 0; i < 4; ++i)
            af[i] = *(const bf16x8*)(At + (h * 64 + i * 16 + lc) * 64 + ((lg ^ psw) * 16));
#pragma unroll
        for (int j = 0; j < 8; ++j)
            bfr[j] = *(const bf16x8*)(Bt + (q * 128 + j * 16 + lc) * 64 + ((lg ^ psw) * 16));
#pragma unroll
        for (int i = 0; i < 4; ++i)
#pragma unroll
            for (int j = 0; j < 8; ++j)
                acc[i][j] = __builtin_amdgcn_mfma_f32_16x16x32_bf16(af[i], bfr[j], acc[i][j], 0, 0, 0);
    }
    __syncthreads();

    // ---- epilogue pass 1: exp + per-wave (T,Te) partials ----
#pragma unroll
    for (int i = 0; i < 4; ++i) {
#pragma unroll
        for (int r = 0; r < 4; ++r) {
            const int m = h * 64 + i * 16 + lg * 4 + r;
            const uint4 w4 = *(const uint4*)(bitsL + m * 16 + q * 4);
            float T = 0.f, Te = 0.f;
#pragma unroll
            for (int j = 0; j < 8; ++j) {
                float e = __expf(acc[i][j][r]);
                acc[i][j][r] = e;
                unsigned word = (j < 2) ? w4.x : (j < 4) ? w4.y : (j < 6) ? w4.z : w4.w;
                float bit = (float)((word >> ((j & 1) * 16 + lc)) & 1u);
                T += e; Te += e * bit;
            }
#pragma unroll
            for (int off = 1; off < 16; off <<= 1) {
                T  += __shfl_xor(T, off);
                Te += __shfl_xor(Te, off);
            }
            if (lc == 0) red[m * 4 + q] = make_float2(T, Te);
        }
    }
    __syncthreads();

    // ---- epilogue pass 2: 8 groups of 16 rows, transpose via stg, coalesced stores ----
    for (int p = 0; p < 8; ++p) {
        if (h == (p >> 2)) {
            const int i = p & 3;
#pragma unroll
            for (int r = 0; r < 4; ++r) {
                const int m = h * 64 + i * 16 + lg * 4 + r;
                float2 p0 = red[m * 4 + 0], p1 = red[m * 4 + 1];
                float2 p2 = red[m * 4 + 2], p3 = red[m * 4 + 3];
                float T  = p0.x + p1.x + p2.x + p3.x;
                float Te = p0.y + p1.y + p2.y + p3.y;
                const float inv = 1.0f / (Te + 1e-10f * (T - Te));
                const uint4 w4 = *(const uint4*)(bitsL + m * 16 + q * 4);
#pragma unroll
                for (int j = 0; j < 8; ++j) {
                    unsigned word = (j < 2) ? w4.x : (j < 4) ? w4.y : (j < 6) ? w4.z : w4.w;
                    unsigned bit = (word >> ((j & 1) * 16 + lc)) & 1u;
                    stg[(lg * 4 + r) * 516 + q * 128 + j * 16 + lc] =
                        bit ? acc[i][j][r] * inv : 0.0f;
                }
            }
        }
        __syncthreads();
#pragma unroll
        for (int it2 = 0; it2 < 4; ++it2) {
            int f = it2 * 512 + t;            // 2048 float4 = 16 rows x 512 f32
            int ml = f >> 7;
            int s4 = (f & 127) * 4;
            float4 v = *(const float4*)(stg + ml * 516 + s4);
            *(float4*)(out + ((size_t)(b * MAXLEN + m0 + p * 16 + ml)) * SEQ + s4) = v;
        }
        __syncthreads();
    }
}

extern "C" void kernel_launch(void* const* d_in, const int* in_sizes, int n_in,
                              void* d_out, int out_size, void* d_ws, size_t ws_size,
                              hipStream_t stream) {
    const float* Mg = (const float*)d_in[0];
    const float* Wg = (const float*)d_in[1];
    // d_in[2] = lengths (unused by reference)
    const int* eb = (const int*)d_in[3];
    const int* eu = (const int*)d_in[4];
    const int* ev = (const int*)d_in[5];
    const int E = in_sizes[3];

    float* out = (float*)d_out;
    unsigned int* bits = (unsigned int*)d_ws;   // 32768 rows * 16 words = 2 MB

    (void)hipMemsetAsync(bits, 0, (size_t)BATCH * MAXLEN * 16 * sizeof(unsigned int), stream);
    edge_scatter<<<(E + 255) / 256, 256, 0, stream>>>(eb, eu, ev, bits, E);
    fused_attn<<<256, 512, 0, stream>>>(Mg, Wg, bits, out);
}

// Round 10
// 97.376 us; speedup vs baseline: 1.0949x; 1.0479x over previous
//
#include <hip/hip_runtime.h>
#include <hip/hip_bf16.h>

// SEQ=512, BATCH=64, DIM=512, MAXLEN=512, E=655360
// out[b][u][s] = edge(b,u,s) ? exp(scale) / (T_e + 1e-10*(T-T_e)) : 0  (max cancels)
// scale[s,b,m] = sum_d M[s,b,d] * W[m,d]
//
// Primary: prep transposes M -> Mbf[b][s][d] bf16 (contiguous per-b panels;
// kills the 64-128KB-stride small-request pattern that capped HBM/L2), cvt W,
// builds edge bitmap. fused_attn_p: block = (b, m-tile 64) x s=512; 8 waves,
// wave owns a 64-row s-band. A resident in LDS (64 KB swizzled, conflict-free
// staged); B bands DMA'd 3-deep via global_load_lds, per-wave counted vmcnt,
// ZERO barriers in K-loop. Fallback (round-6) if ws too small.

#define SEQ 512
#define BATCH 64
#define DIM 512
#define MAXLEN 512

typedef __attribute__((ext_vector_type(8))) __bf16 bf16x8;
typedef __attribute__((ext_vector_type(4))) float f32x4;

__device__ __forceinline__ unsigned cvt_pk(float lo, float hi) {
    unsigned r;
    asm("v_cvt_pk_bf16_f32 %0, %1, %2" : "=v"(r) : "v"(lo), "v"(hi));
    return r;
}

__device__ __forceinline__ void gload16(const void* g, void* l) {
    __builtin_amdgcn_global_load_lds(
        (const __attribute__((address_space(1))) void*)g,
        (__attribute__((address_space(3))) void*)l, 16, 0, 0);
}

// ================= primary path =================

// blocks 0..2047: transpose-cvt M -> Mbf[b][s][d]
// blocks 2048..4607: edge scatter
// blocks 4608..4735: cvt W -> Wbf
__global__ __launch_bounds__(256) void prep(const float* __restrict__ Mg,
                                            const float* __restrict__ Wg,
                                            const int* __restrict__ eb,
                                            const int* __restrict__ eu,
                                            const int* __restrict__ ev,
                                            unsigned short* __restrict__ Mbf,
                                            unsigned short* __restrict__ Wbf,
                                            unsigned* __restrict__ bits, int E) {
    const int blk = blockIdx.x;
    const int t = threadIdx.x;
    if (blk < 2048) {
        const int b = blk >> 5;
        const int sg = blk & 31;
        const int s = sg * 16 + (t >> 4);
        const int l16 = t & 15;
        const float* src = Mg + ((size_t)s * BATCH + b) * DIM + l16 * 32;
        char* dst = (char*)Mbf + ((size_t)(b * SEQ + s)) * 1024 + l16 * 64;
#pragma unroll
        for (int c4 = 0; c4 < 4; ++c4) {
            float4 a = *(const float4*)(src + c4 * 8);
            float4 c = *(const float4*)(src + c4 * 8 + 4);
            uint4 o;
            o.x = cvt_pk(a.x, a.y); o.y = cvt_pk(a.z, a.w);
            o.z = cvt_pk(c.x, c.y); o.w = cvt_pk(c.z, c.w);
            *(uint4*)(dst + c4 * 16) = o;
        }
    } else if (blk < 4608) {
        int i = (blk - 2048) * 256 + t;
        if (i < E)
            atomicOr(&bits[(eb[i] * MAXLEN + eu[i]) * 16 + (ev[i] >> 5)],
                     1u << (ev[i] & 31));
    } else {
        size_t id = (size_t)(blk - 4608) * 256 + t;   // 32768 x 8 floats
        const float4* s = (const float4*)Wg + id * 2;
        float4 a = s[0], c = s[1];
        uint4 o;
        o.x = cvt_pk(a.x, a.y); o.y = cvt_pk(a.z, a.w);
        o.z = cvt_pk(c.x, c.y); o.w = cvt_pk(c.z, c.w);
        ((uint4*)Wbf)[id] = o;
    }
}

__global__ __launch_bounds__(512, 1) void fused_attn_p(
    const unsigned short* __restrict__ Mbf,
    const unsigned short* __restrict__ Wbf,
    const unsigned int* __restrict__ bitsG,
    float* __restrict__ out) {
    // LDS (160 KiB exactly):
    //   [0,65536):      A 64 rows x 1024 B; LDS chunk c of row r holds src chunk c^(r&7)
    //   [65536,163840): B 3 bufs x 8 waves x (64 rows x 64 B); LDS chunk c of row r
    //                   holds src chunk c^((r>>1)&3)
    //   epilogue overlays: red float2[64][8] at +65536; stg [16][516] f32 at 0
    __shared__ __align__(16) char lds[163840];

    const int g = blockIdx.x;
    const int work = (g & 7) * 64 + (g >> 3);   // bijective [0,512): same-b -> one XCD
    const int b  = work >> 3;
    const int m0 = (work & 7) * 64;

    const int t = threadIdx.x, lane = t & 63, wv = t >> 6;
    const int lg = lane >> 4, lc = lane & 15;

    // ---- B DMA source (swizzle folded into per-lane source chunk) ----
    const int srow = wv * 64 + (lane >> 2);                 // + q*16 rows
    const int cs   = (lane & 3) ^ ((lane >> 3) & 3);        // source chunk in 64B slice
    const char* bsrc = (const char*)Mbf + ((size_t)(b * SEQ + srow)) * 1024 + cs * 16;
    char* const bband0 = lds + 65536 + wv * 4096;           // + p*32768 + q*1024

    // prologue: issue B(0),B(1),B(2)  (k-chunk p*64 within each 1KB row)
#pragma unroll
    for (int p = 0; p < 3; ++p)
#pragma unroll
        for (int q = 0; q < 4; ++q)
            gload16(bsrc + ((size_t)q << 14) + p * 64, bband0 + p * 32768 + q * 1024);

    // ---- stage whole A tile (64 x 512 bf16), conflict-free writes ----
    {
        const char* wb = (const char*)Wbf + (size_t)m0 * 1024;
        const int r = t >> 3;                 // 0..63
#pragma unroll
        for (int i = 0; i < 8; ++i) {
            int ch  = (t & 7) + 8 * i;        // 8 lanes span 8 bank-quads
            int csA = ch ^ (r & 7);
            uint4 v = *(const uint4*)(wb + (size_t)r * 1024 + csA * 16);
            *(uint4*)(lds + r * 1024 + ch * 16) = v;
        }
    }
    __syncthreads();   // A visible (prologue DMAs also drain here; once, acceptable)

    f32x4 acc[4][4] = {};

#pragma unroll
    for (int ks = 0; ks < 16; ++ks) {
        if (ks <= 13)      asm volatile("s_waitcnt vmcnt(8)" ::: "memory");
        else if (ks == 14) asm volatile("s_waitcnt vmcnt(4)" ::: "memory");
        else               asm volatile("s_waitcnt vmcnt(0)" ::: "memory");

        const char* bb = lds + 65536 + (ks % 3) * 32768 + wv * 4096;
        bf16x8 af[4], bfr[4];
#pragma unroll
        for (int i = 0; i < 4; ++i) {
            int r  = i * 16 + lc;
            int ch = (ks * 4 + lg) ^ (lc & 7);
            af[i] = *(const bf16x8*)(lds + r * 1024 + ch * 16);
        }
#pragma unroll
        for (int j = 0; j < 4; ++j) {
            int r  = j * 16 + lc;
            int ch = lg ^ ((lc >> 1) & 3);
            bfr[j] = *(const bf16x8*)(bb + r * 64 + ch * 16);
        }
#pragma unroll
        for (int i = 0; i < 4; ++i)
#pragma unroll
            for (int j = 0; j < 4; ++j)
                acc[i][j] = __builtin_amdgcn_mfma_f32_16x16x32_bf16(af[i], bfr[j], acc[i][j], 0, 0, 0);

        if (ks + 3 < 16) {
            __builtin_amdgcn_sched_barrier(0);   // keep issues after this step's reads
#pragma unroll
            for (int q = 0; q < 4; ++q)
                gload16(bsrc + ((size_t)q << 14) + (ks + 3) * 64,
                        bband0 + (ks % 3) * 32768 + q * 1024);
        }
    }

    __syncthreads();   // all waves done with B region before red overlay

    float2* const red = (float2*)(lds + 65536);
    // ---- pass 1: exp + per-wave (T,Te) partials ----
#pragma unroll
    for (int i = 0; i < 4; ++i) {
#pragma unroll
        for (int r = 0; r < 4; ++r) {
            const int m = i * 16 + lg * 4 + r;
            const uint2 wbt = *(const uint2*)(bitsG + (size_t)(b * MAXLEN + m0 + m) * 16 + wv * 2);
            float T = 0.f, Te = 0.f;
#pragma unroll
            for (int j = 0; j < 4; ++j) {
                float e = __expf(acc[i][j][r]);
                acc[i][j][r] = e;
                unsigned word = (j & 2) ? wbt.y : wbt.x;
                float bit = (float)((word >> ((j & 1) * 16 + lc)) & 1u);
                T += e; Te += e * bit;
            }
#pragma unroll
            for (int off = 1; off < 16; off <<= 1) {
                T  += __shfl_xor(T, off);
                Te += __shfl_xor(Te, off);
            }
            if (lc == 0) red[m * 8 + wv] = make_float2(T, Te);
        }
    }
    __syncthreads();

    // ---- pass 2: masked scale -> LDS transpose -> coalesced full-line stores ----
    float* const stg = (float*)lds;
    for (int i = 0; i < 4; ++i) {
        float inv[4];
        uint2 wbt2[4];
#pragma unroll
        for (int r = 0; r < 4; ++r) {
            const int m = i * 16 + lg * 4 + r;
            float T = 0.f, Te = 0.f;
#pragma unroll
            for (int q = 0; q < 8; ++q) {
                float2 p = red[m * 8 + q];
                T += p.x; Te += p.y;
            }
            inv[r] = 1.0f / (Te + 1e-10f * (T - Te));
            wbt2[r] = *(const uint2*)(bitsG + (size_t)(b * MAXLEN + m0 + m) * 16 + wv * 2);
        }
#pragma unroll
        for (int r = 0; r < 4; ++r) {
#pragma unroll
            for (int j = 0; j < 4; ++j) {
                unsigned word = (j & 2) ? wbt2[r].y : wbt2[r].x;
                unsigned bit = (word >> ((j & 1) * 16 + lc)) & 1u;
                stg[(lg * 4 + r) * 516 + wv * 64 + j * 16 + lc] =
                    bit ? acc[i][j][r] * inv[r] : 0.0f;
            }
        }
        __syncthreads();
#pragma unroll
        for (int it = 0; it < 4; ++it) {
            int f = it * 512 + t;
            int ml = f >> 7;
            int s4 = (f & 127) * 4;
            float4 v = *(const float4*)(stg + ml * 516 + s4);
            *(float4*)(out + ((size_t)(b * MAXLEN + m0 + i * 16 + ml)) * SEQ + s4) = v;
        }
        __syncthreads();
    }
}

// ================= fallback path (round-6, known-correct) =================

__global__ __launch_bounds__(256) void edge_scatter(const int* __restrict__ eb,
                                                    const int* __restrict__ eu,
                                                    const int* __restrict__ ev,
                                                    unsigned int* __restrict__ bits,
                                                    int E) {
    int i = blockIdx.x * 256 + threadIdx.x;
    if (i < E) {
        int b = eb[i], u = eu[i], v = ev[i];
        atomicOr(&bits[(b * MAXLEN + u) * 16 + (v >> 5)], 1u << (v & 31));
    }
}

__global__ __launch_bounds__(256) void cvt_w(const float* __restrict__ src,
                                             unsigned short* __restrict__ dst) {
    int i = blockIdx.x * 256 + threadIdx.x;
    const float4* s = (const float4*)src + (size_t)i * 2;
    float4 a = s[0], c = s[1];
    uint4 o;
    o.x = cvt_pk(a.x, a.y); o.y = cvt_pk(a.z, a.w);
    o.z = cvt_pk(c.x, c.y); o.w = cvt_pk(c.z, c.w);
    ((uint4*)dst)[i] = o;
}

__global__ __launch_bounds__(512, 4) void fused_attn(
    const float* __restrict__ Mg,
    const unsigned short* __restrict__ Wbf,
    const unsigned int* __restrict__ bitsG,
    float* __restrict__ out) {
    __shared__ __align__(16) char lds[81920];
    char* bufB  = lds;
    char* curA  = lds + 65536;
    char* nxtA  = lds + 69632;
    float2* red = (float2*)(lds + 73728);
    unsigned* bitsL = (unsigned*)(lds + 77824);
    float* stg = (float*)lds;

    const int g = blockIdx.x;
    const int work = (g & 7) * 64 + (g >> 3);
    const int b  = work >> 3;
    const int m0 = (work & 7) * 64;

    const int t = threadIdx.x;
    const int lane = t & 63;
    const int wv = t >> 6;
    const int lg = lane >> 4;
    const int lc = lane & 15;

    if (t < 256)
        ((uint4*)bitsL)[t] = ((const uint4*)(bitsG + (size_t)(b * MAXLEN + m0) * 16))[t];

    const int brs = lane >> 3;
    const int bc  = (lane & 7) ^ brs;
    const int ars = lane >> 2;
    const int ac  = (lane & 3) ^ ((ars >> 2) & 3);

    const char* const MgB = (const char*)Mg + (size_t)b * DIM * 4;
    const char* const WbB = (const char*)Wbf + (size_t)m0 * DIM * 2;

    f32x4 acc[4][4] = {};

    if (wv < 4)
        gload16(WbB + (size_t)(wv * 16 + ars) * (DIM * 2) + ac * 16, curA + wv * 16 * 64);
    __syncthreads();

#pragma unroll 2
    for (int ks = 0; ks < 16; ++ks) {
        const int kb = ks * 128;
#pragma unroll
        for (int q = 0; q < 8; ++q) {
            int r = wv * 64 + q * 8 + brs;
            gload16(MgB + (size_t)r * (BATCH * DIM * 4) + kb + bc * 16,
                    bufB + (wv * 64 + q * 8) * 128);
        }
        const bool pfA = (ks < 15) && (wv < 4);
        if (pfA)
            gload16(WbB + (size_t)(wv * 16 + ars) * (DIM * 2) + (ks + 1) * 64 + ac * 16,
                    nxtA + wv * 16 * 64);
        if (pfA) asm volatile("s_waitcnt vmcnt(1)" ::: "memory");
        else     asm volatile("s_waitcnt vmcnt(0)" ::: "memory");

        const int fxr = (lc >> 2) & 3;
        bf16x8 af[4];
#pragma unroll
        for (int i = 0; i < 4; ++i)
            af[i] = *(const bf16x8*)(curA + (i * 16 + lc) * 64 + ((lg ^ fxr) * 16));
        const int bxr = lc & 7;
        bf16x8 bfr[4];
#pragma unroll
        for (int j = 0; j < 4; ++j) {
            const char* rowp = bufB + (wv * 64 + j * 16 + lc) * 128;
            f32x4 x = *(const f32x4*)(rowp + (((2 * lg) ^ bxr) * 16));
            f32x4 y = *(const f32x4*)(rowp + (((2 * lg + 1) ^ bxr) * 16));
            uint4 pk;
            pk.x = cvt_pk(x[0], x[1]); pk.y = cvt_pk(x[2], x[3]);
            pk.z = cvt_pk(y[0], y[1]); pk.w = cvt_pk(y[2], y[3]);
            bfr[j] = __builtin_bit_cast(bf16x8, pk);
        }
#pragma unroll
        for (int i = 0; i < 4; ++i)
#pragma unroll
            for (int j = 0; j < 4; ++j)
                acc[i][j] = __builtin_amdgcn_mfma_f32_16x16x32_bf16(af[i], bfr[j], acc[i][j], 0, 0, 0);
        __syncthreads();
        { char* tmp = curA; curA = nxtA; nxtA = tmp; }
    }

#pragma unroll
    for (int i = 0; i < 4; ++i) {
#pragma unroll
        for (int r = 0; r < 4; ++r) {
            const int m = i * 16 + lg * 4 + r;
            const uint2 wbt = *(const uint2*)(bitsL + m * 16 + wv * 2);
            float T = 0.f, Te = 0.f;
#pragma unroll
            for (int j = 0; j < 4; ++j) {
                float e = __expf(acc[i][j][r]);
                acc[i][j][r] = e;
                unsigned word = (j & 2) ? wbt.y : wbt.x;
                float bit = (float)((word >> ((j & 1) * 16 + lc)) & 1u);
                T += e; Te += e * bit;
            }
#pragma unroll
            for (int off = 1; off < 16; off <<= 1) {
                T  += __shfl_xor(T, off);
                Te += __shfl_xor(Te, off);
            }
            if (lc == 0) red[m * 8 + wv] = make_float2(T, Te);
        }
    }
    __syncthreads();

    for (int i = 0; i < 4; ++i) {
        float inv[4];
        uint2 wbt2[4];
#pragma unroll
        for (int r = 0; r < 4; ++r) {
            const int m = i * 16 + lg * 4 + r;
            float T = 0.f, Te = 0.f;
#pragma unroll
            for (int q = 0; q < 8; ++q) {
                float2 p = red[m * 8 + q];
                T += p.x; Te += p.y;
            }
            inv[r] = 1.0f / (Te + 1e-10f * (T - Te));
            wbt2[r] = *(const uint2*)(bitsL + m * 16 + wv * 2);
        }
#pragma unroll
        for (int r = 0; r < 4; ++r) {
#pragma unroll
            for (int j = 0; j < 4; ++j) {
                unsigned word = (j & 2) ? wbt2[r].y : wbt2[r].x;
                unsigned bit = (word >> ((j & 1) * 16 + lc)) & 1u;
                stg[(lg * 4 + r) * 516 + wv * 64 + j * 16 + lc] =
                    bit ? acc[i][j][r] * inv[r] : 0.0f;
            }
        }
        __syncthreads();
#pragma unroll
        for (int it = 0; it < 4; ++it) {
            int f = it * 512 + t;
            int ml = f >> 7;
            int s4 = (f & 127) * 4;
            float4 v = *(const float4*)(stg + ml * 516 + s4);
            *(float4*)(out + ((size_t)(b * MAXLEN + m0 + i * 16 + ml)) * SEQ + s4) = v;
        }
        __syncthreads();
    }
}

// ================= launch =================

extern "C" void kernel_launch(void* const* d_in, const int* in_sizes, int n_in,
                              void* d_out, int out_size, void* d_ws, size_t ws_size,
                              hipStream_t stream) {
    const float* Mg = (const float*)d_in[0];
    const float* Wg = (const float*)d_in[1];
    // d_in[2] = lengths (unused by reference)
    const int* eb = (const int*)d_in[3];
    const int* eu = (const int*)d_in[4];
    const int* ev = (const int*)d_in[5];
    const int E = in_sizes[3];

    float* out = (float*)d_out;
    unsigned int* bits = (unsigned int*)d_ws;
    const size_t MBF_OFF = 2097152;                       // 2 MB bitmap
    const size_t WBF_OFF = MBF_OFF + 33554432;            // + 32 MB Mbf
    const size_t NEED    = WBF_OFF + 524288;              // + 0.5 MB Wbf

    (void)hipMemsetAsync(bits, 0, (size_t)BATCH * MAXLEN * 16 * sizeof(unsigned int), stream);

    if (ws_size >= NEED) {
        unsigned short* Mbf = (unsigned short*)((char*)d_ws + MBF_OFF);
        unsigned short* Wbf = (unsigned short*)((char*)d_ws + WBF_OFF);
        prep<<<4736, 256, 0, stream>>>(Mg, Wg, eb, eu, ev, Mbf, Wbf, bits, E);
        fused_attn_p<<<512, 512, 0, stream>>>(Mbf, Wbf, bits, out);
    } else {
        unsigned short* Wbf = (unsigned short*)((char*)d_ws + MBF_OFF);
        edge_scatter<<<(E + 255) / 256, 256, 0, stream>>>(eb, eu, ev, bits, E);
        cvt_w<<<128, 256, 0, stream>>>(Wg, Wbf);
        fused_attn<<<512, 512, 0, stream>>>(Mg, Wbf, bits, out);
    }
}